// Round 7
// baseline (1111.187 us; speedup 1.0000x reference)
//
#include <hip/hip_runtime.h>

#define NB 8
#define NN 2048
#define MM 2048
#define DD 64
#define NMAT ((size_t)NN * (size_t)MM)
#define NCHK 16
#define TS 128

// uint16 fixed-point encoding of C (verified exact enough: rounds 5/6 absmax 0.0)
#define CSCALE 320.0f
#define CDEC   (1.0f / CSCALE)

// ---------------------------------------------------------------------------
// Static device scratch. Three u16 cost slabs (201 MB); per-iteration reads
// touch only 135 MB (Cxy full + upper triangles of Cxx/Cyy).
// ---------------------------------------------------------------------------
__device__ unsigned short g_C[3 * NB * NMAT];   // Cxy|Cxx|Cyy
// potential banks: [0]/[1] = carry double-buffer, [2] = final
__device__ float g_fab[3][NB * NN], g_gba[3][NB * NN];
__device__ float g_faa[3][NB * NN], g_gbb[3][NB * NN];
__device__ float g_alog[NB * NN], g_blog[NB * NN];
__device__ float g_xn[NB * NN], g_yn[NB * NN];
__device__ float g_h0[NB * MM], g_h1[NB * NN], g_h2[NB * NN], g_h3[NB * MM];
// chunked softmin partials (m,s): [b][chunk][row]
__device__ float2 g_pfab[NB * NCHK * NN];
__device__ float2 g_pgba[NB * NCHK * NN];
__device__ float2 g_pfaa[NB * NCHK * NN];
__device__ float2 g_pgbb[NB * NCHK * NN];

// ---------------------------------------------------------------------------
// prep: a_log/b_log = log(w), xn/yn = 0.5*||row||^2 (one row per wave)
// ---------------------------------------------------------------------------
__global__ __launch_bounds__(256) void prep_kernel(
    const float* __restrict__ x, const float* __restrict__ y,
    const float* __restrict__ w1, const float* __restrict__ w2)
{
  int gid = blockIdx.x * 256 + threadIdx.x;
  if (gid < NB * NN) {
    g_alog[gid] = logf(w1[gid]);
    g_blog[gid] = logf(w2[gid]);
  }
  int lane = threadIdx.x & 63;
  int row = blockIdx.x * 4 + (threadIdx.x >> 6);   // grid 4096 -> rows 0..16383
  float xv = x[(size_t)row * DD + lane];
  float yv = y[(size_t)row * DD + lane];
  float sx = xv * xv;
  float sy = yv * yv;
#pragma unroll
  for (int off = 32; off > 0; off >>= 1) {
    sx += __shfl_down(sx, off);
    sy += __shfl_down(sy, off);
  }
  if (lane == 0) {
    g_xn[row] = 0.5f * sx;
    g_yn[row] = 0.5f * sy;
  }
}

// ---------------------------------------------------------------------------
// cost GEMM: C[b][i][j] = max(xn_i + yn_j - x_i . y_j, 0), uint16 out.
// (verified round 5/6; unchanged)
// ---------------------------------------------------------------------------
__global__ __launch_bounds__(256) void cost_kernel(
    const float* __restrict__ X, const float* __restrict__ Y,
    const float* __restrict__ xn, const float* __restrict__ yn,
    unsigned short* __restrict__ C)
{
  __shared__ float Xs[32 * 128];
  __shared__ float Ys[32 * 128];
  const int b = blockIdx.z;
  const int i0 = blockIdx.y * 128;
  const int j0 = blockIdx.x * 128;
  const int t = threadIdx.x;
  const float* xb = X + (size_t)b * NN * DD;
  const float* yb = Y + (size_t)b * MM * DD;
  const int tx = t & 15, ty = t >> 4;

  float acc[8][8];
#pragma unroll
  for (int r = 0; r < 8; ++r)
#pragma unroll
    for (int c = 0; c < 8; ++c) acc[r][c] = 0.f;

  for (int kk = 0; kk < 64; kk += 32) {
    if (kk) __syncthreads();
#pragma unroll
    for (int p = 0; p < 4; ++p) {
      int f = p * 256 + t;
      int r = f >> 3;
      int k4 = (f & 7) << 2;
      float4 vx = ((const float4*)(xb + (size_t)(i0 + r) * DD))[(kk >> 2) + (f & 7)];
      int rs = r ^ k4;
      Xs[(k4 + 0) * 128 + rs] = vx.x;
      Xs[(k4 + 1) * 128 + rs] = vx.y;
      Xs[(k4 + 2) * 128 + rs] = vx.z;
      Xs[(k4 + 3) * 128 + rs] = vx.w;
      float4 vy = ((const float4*)(yb + (size_t)(j0 + r) * DD))[(kk >> 2) + (f & 7)];
      Ys[(k4 + 0) * 128 + rs] = vy.x;
      Ys[(k4 + 1) * 128 + rs] = vy.y;
      Ys[(k4 + 2) * 128 + rs] = vy.z;
      Ys[(k4 + 3) * 128 + rs] = vy.w;
    }
    __syncthreads();

#pragma unroll 4
    for (int k = 0; k < 32; ++k) {
      int s = k & 28;
      float a[8], bb[8];
      *(float4*)&a[0]  = *(const float4*)&Xs[k * 128 + ((ty * 8) ^ s)];
      *(float4*)&a[4]  = *(const float4*)&Xs[k * 128 + ((ty * 8 + 4) ^ s)];
      *(float4*)&bb[0] = *(const float4*)&Ys[k * 128 + ((tx * 8) ^ s)];
      *(float4*)&bb[4] = *(const float4*)&Ys[k * 128 + ((tx * 8 + 4) ^ s)];
#pragma unroll
      for (int r = 0; r < 8; ++r)
#pragma unroll
        for (int c = 0; c < 8; ++c)
          acc[r][c] = fmaf(a[r], bb[c], acc[r][c]);
    }
  }

  float xr[8], yc[8];
#pragma unroll
  for (int r = 0; r < 8; ++r) xr[r] = xn[b * NN + i0 + ty * 8 + r];
#pragma unroll
  for (int c = 0; c < 8; ++c) yc[c] = yn[b * MM + j0 + tx * 8 + c];

#pragma unroll
  for (int r = 0; r < 8; ++r) {
    unsigned short* crow = C + (size_t)b * NMAT
                         + (size_t)(i0 + ty * 8 + r) * MM + j0 + tx * 8;
    unsigned int u[8];
#pragma unroll
    for (int c = 0; c < 8; ++c) {
      float cv = fmaxf(xr[r] + yc[c] - acc[r][c], 0.f);
      u[c] = __float2uint_rn(fminf(cv * CSCALE, 65535.f));
    }
    uint4 ow;
    ow.x = u[0] | (u[1] << 16);
    ow.y = u[2] | (u[3] << 16);
    ow.z = u[4] | (u[5] << 16);
    ow.w = u[6] | (u[7] << 16);
    *(uint4*)crow = ow;
  }
}

// ---------------------------------------------------------------------------
// h-vector prep (verified, unchanged):
//   h0 = blog + gs*gba_in ; h1 = alog + gs*fab_in
//   h2 = alog + gs*faa_in ; h3 = blog + gs*gbb_in
// ---------------------------------------------------------------------------
__global__ __launch_bounds__(256) void hprep_kernel(
    const float* __restrict__ fab_in, const float* __restrict__ gba_in,
    const float* __restrict__ faa_in, const float* __restrict__ gbb_in,
    float gs)
{
  int i = blockIdx.x * 256 + threadIdx.x;   // grid 64 -> 16384
  g_h0[i] = fmaf(gs, gba_in[i], g_blog[i]);
  g_h1[i] = fmaf(gs, fab_in[i], g_alog[i]);
  g_h2[i] = fmaf(gs, faa_in[i], g_alog[i]);
  g_h3[i] = fmaf(gs, gbb_in[i], g_blog[i]);
}

// ---------------------------------------------------------------------------
// Unified tile-partial softmin pass. One block = one 128x128 tile; computes
// BOTH row-direction (v = hrow[j] - C[i,j]/eps, partial over this col-chunk)
// and col-direction (v = hcol[i] - C[i,j]/eps, partial over this row-chunk)
// (m, s) partials in a two-phase max-then-sum (exact shifts; same math as the
// verified row kernel, grouped by chunk). For symmetric slabs (Cxx/Cyy) only
// upper-triangle tiles run; col-dir covers the mirrored chunks.
// Phase B re-reads the tile from global (L2-hot) instead of staging in LDS.
// ---------------------------------------------------------------------------
struct TileArgs {
  const unsigned short* C;
  const float* hrow;
  const float* hcol;
  float2* prow;   // [b][chunk][row]
  float2* pcol;
  int sym;        // 1 => triangular tile enumeration (136 tiles)
};

__global__ __launch_bounds__(256) void tile_pass(
    TileArgs T0, TileArgs T1, TileArgs T2, float inv_eps)
{
  TileArgs A = (blockIdx.z == 0) ? T0 : (blockIdx.z == 1) ? T1 : T2;
  int I, J;
  if (A.sym) {
    if (blockIdx.x >= 136) return;
    int rem = blockIdx.x, ii = 0;
    while (rem >= NCHK - ii) { rem -= NCHK - ii; ++ii; }   // uniform, <=16 iters
    I = ii; J = ii + rem;                                  // I <= J
  } else {
    I = blockIdx.x >> 4;
    J = blockIdx.x & 15;
  }
  const int b = blockIdx.y;
  const int t = threadIdx.x;
  const int ctr = t & 15;   // col-group: tile cols ctr*8 .. +7
  const int rtr = t >> 4;   // row-group: tile rows rtr*8 .. +7
  const float csneg = -inv_eps * CDEC;

  const unsigned short* Cb = A.C + (size_t)b * NMAT
                           + (size_t)(I * TS) * MM + J * TS;

  float hr[8], hc[8];
  {
    const float* hrp = A.hrow + (size_t)b * MM + J * TS + ctr * 8;
    const float* hcp = A.hcol + (size_t)b * MM + I * TS + rtr * 8;
#pragma unroll
    for (int k = 0; k < 8; ++k) { hr[k] = hrp[k]; hc[k] = hcp[k]; }
  }

  __shared__ float redR[TS][17], redC[TS][17];   // +1 pad vs bank conflicts
  __shared__ float rowM[TS], colM[TS];

  // ---- phase A: maxes ----
  float rm[8], cm[8];
#pragma unroll
  for (int k = 0; k < 8; ++k) { rm[k] = -3.0e38f; cm[k] = -3.0e38f; }

#pragma unroll
  for (int r8 = 0; r8 < 8; ++r8) {
    uint4 cu = *(const uint4*)(Cb + (size_t)(rtr * 8 + r8) * MM + ctr * 8);
    float base[8];
    base[0] = (float)(cu.x & 0xffff) * csneg;
    base[1] = (float)(cu.x >> 16)    * csneg;
    base[2] = (float)(cu.y & 0xffff) * csneg;
    base[3] = (float)(cu.y >> 16)    * csneg;
    base[4] = (float)(cu.z & 0xffff) * csneg;
    base[5] = (float)(cu.z >> 16)    * csneg;
    base[6] = (float)(cu.w & 0xffff) * csneg;
    base[7] = (float)(cu.w >> 16)    * csneg;
#pragma unroll
    for (int c8 = 0; c8 < 8; ++c8) {
      rm[r8] = fmaxf(rm[r8], hr[c8] + base[c8]);
      cm[c8] = fmaxf(cm[c8], hc[r8] + base[c8]);
    }
  }
#pragma unroll
  for (int r8 = 0; r8 < 8; ++r8) redR[rtr * 8 + r8][ctr] = rm[r8];
#pragma unroll
  for (int c8 = 0; c8 < 8; ++c8) redC[ctr * 8 + c8][rtr] = cm[c8];
  __syncthreads();
  if (t < TS) {
    float m = redR[t][0];
#pragma unroll
    for (int k = 1; k < 16; ++k) m = fmaxf(m, redR[t][k]);
    rowM[t] = m;
  } else {
    int tt = t - TS;
    float m = redC[tt][0];
#pragma unroll
    for (int k = 1; k < 16; ++k) m = fmaxf(m, redC[tt][k]);
    colM[tt] = m;
  }
  __syncthreads();

  float rmv[8], cmv[8];
#pragma unroll
  for (int k = 0; k < 8; ++k) {
    rmv[k] = rowM[rtr * 8 + k];
    cmv[k] = colM[ctr * 8 + k];
  }

  // ---- phase B: sums (tile re-read is L2-hot) ----
  float rs[8], cs[8];
#pragma unroll
  for (int k = 0; k < 8; ++k) { rs[k] = 0.f; cs[k] = 0.f; }
#pragma unroll
  for (int r8 = 0; r8 < 8; ++r8) {
    uint4 cu = *(const uint4*)(Cb + (size_t)(rtr * 8 + r8) * MM + ctr * 8);
    float base[8];
    base[0] = (float)(cu.x & 0xffff) * csneg;
    base[1] = (float)(cu.x >> 16)    * csneg;
    base[2] = (float)(cu.y & 0xffff) * csneg;
    base[3] = (float)(cu.y >> 16)    * csneg;
    base[4] = (float)(cu.z & 0xffff) * csneg;
    base[5] = (float)(cu.z >> 16)    * csneg;
    base[6] = (float)(cu.w & 0xffff) * csneg;
    base[7] = (float)(cu.w >> 16)    * csneg;
#pragma unroll
    for (int c8 = 0; c8 < 8; ++c8) {
      rs[r8] += __expf(hr[c8] + base[c8] - rmv[r8]);
      cs[c8] += __expf(hc[r8] + base[c8] - cmv[c8]);
    }
  }
#pragma unroll
  for (int r8 = 0; r8 < 8; ++r8) redR[rtr * 8 + r8][ctr] = rs[r8];
#pragma unroll
  for (int c8 = 0; c8 < 8; ++c8) redC[ctr * 8 + c8][rtr] = cs[c8];
  __syncthreads();
  if (t < TS) {
    float s = 0.f;
#pragma unroll
    for (int k = 0; k < 16; ++k) s += redR[t][k];
    A.prow[((size_t)b * NCHK + J) * NN + I * TS + t] = make_float2(rowM[t], s);
  } else {
    int tt = t - TS;
    if (!(A.sym && I == J)) {   // diagonal col-dir duplicates row-dir: skip
      float s = 0.f;
#pragma unroll
      for (int k = 0; k < 16; ++k) s += redC[tt][k];
      A.pcol[((size_t)b * NCHK + I) * NN + J * TS + tt] = make_float2(colM[tt], s);
    }
  }
}

// ---------------------------------------------------------------------------
// merge 16 chunk-partials per row -> softmin value + Jacobi update.
// 4 potentials on blockIdx.z. (same math as verified col_merge)
// ---------------------------------------------------------------------------
struct MergeArgs {
  const float2* part;
  const float* fold;
  float* fout;
};

__global__ __launch_bounds__(256) void merge4(
    MergeArgs M0, MergeArgs M1, MergeArgs M2, MergeArgs M3,
    float eps, float alpha, float beta)
{
  MergeArgs A = (blockIdx.z == 0) ? M0 : (blockIdx.z == 1) ? M1
              : (blockIdx.z == 2) ? M2 : M3;
  const int b = blockIdx.y;
  const int i = blockIdx.x * 256 + threadIdx.x;   // grid.x = NN/256
  float2 p[NCHK];
#pragma unroll
  for (int k = 0; k < NCHK; ++k)
    p[k] = A.part[((size_t)b * NCHK + k) * NN + i];
  float M = p[0].x;
#pragma unroll
  for (int k = 1; k < NCHK; ++k) M = fmaxf(M, p[k].x);
  float S = 0.f;
#pragma unroll
  for (int k = 0; k < NCHK; ++k) S += p[k].y * __expf(p[k].x - M);
  float ft = -eps * (M + __logf(S));
  int idx = b * NN + i;
  A.fout[idx] = alpha * A.fold[idx] + beta * ft;
}

// ---------------------------------------------------------------------------
// loss = mean_b [ sum_i w1*(fabf - faaf) + sum_j w2*(gbaf - gbbf) ]
// ---------------------------------------------------------------------------
__global__ __launch_bounds__(256) void loss_kernel(
    const float* __restrict__ w1, const float* __restrict__ w2,
    float* __restrict__ out)
{
  __shared__ float red[256];
  float acc = 0.f;
  for (int idx = threadIdx.x; idx < NB * NN; idx += 256) {
    acc += w1[idx] * (g_fab[2][idx] - g_faa[2][idx])
         + w2[idx] * (g_gba[2][idx] - g_gbb[2][idx]);
  }
  red[threadIdx.x] = acc;
  __syncthreads();
  for (int s = 128; s > 0; s >>= 1) {
    if (threadIdx.x < s) red[threadIdx.x] += red[threadIdx.x + s];
    __syncthreads();
  }
  if (threadIdx.x == 0) out[0] = red[0] * (1.0f / NB);
}

// ---------------------------------------------------------------------------
extern "C" void kernel_launch(void* const* d_in, const int* in_sizes, int n_in,
                              void* d_out, int out_size, void* d_ws, size_t ws_size,
                              hipStream_t stream)
{
  const float* x = (const float*)d_in[0];
  const float* y = (const float*)d_in[1];
  const float* w1 = (const float*)d_in[2];
  const float* w2 = (const float*)d_in[3];
  float* out = (float*)d_out;

  unsigned short* Cbase;
  hipGetSymbolAddress((void**)&Cbase, HIP_SYMBOL(g_C));
  unsigned short* Cxy = Cbase + 0ull * NB * NMAT;
  unsigned short* Cxx = Cbase + 1ull * NB * NMAT;
  unsigned short* Cyy = Cbase + 2ull * NB * NMAT;
  float *xn, *yn, *h0, *h1, *h2, *h3, *fabp, *gbap, *faap, *gbbp;
  float2 *pfab, *pgba, *pfaa, *pgbb;
  hipGetSymbolAddress((void**)&xn, HIP_SYMBOL(g_xn));
  hipGetSymbolAddress((void**)&yn, HIP_SYMBOL(g_yn));
  hipGetSymbolAddress((void**)&h0, HIP_SYMBOL(g_h0));
  hipGetSymbolAddress((void**)&h1, HIP_SYMBOL(g_h1));
  hipGetSymbolAddress((void**)&h2, HIP_SYMBOL(g_h2));
  hipGetSymbolAddress((void**)&h3, HIP_SYMBOL(g_h3));
  hipGetSymbolAddress((void**)&fabp, HIP_SYMBOL(g_fab));
  hipGetSymbolAddress((void**)&gbap, HIP_SYMBOL(g_gba));
  hipGetSymbolAddress((void**)&faap, HIP_SYMBOL(g_faa));
  hipGetSymbolAddress((void**)&gbbp, HIP_SYMBOL(g_gbb));
  hipGetSymbolAddress((void**)&pfab, HIP_SYMBOL(g_pfab));
  hipGetSymbolAddress((void**)&pgba, HIP_SYMBOL(g_pgba));
  hipGetSymbolAddress((void**)&pfaa, HIP_SYMBOL(g_pfaa));
  hipGetSymbolAddress((void**)&pgbb, HIP_SYMBOL(g_pgbb));

  auto fab = [&](int s) { return fabp + (size_t)s * NB * NN; };
  auto gba = [&](int s) { return gbap + (size_t)s * NB * NN; };
  auto faa = [&](int s) { return faap + (size_t)s * NB * NN; };
  auto gbb = [&](int s) { return gbbp + (size_t)s * NB * NN; };

  // eps schedule (matches the Python double loop, then cast to fp32)
  float eps_list[32];
  int ne = 0;
  {
    double v = 64.0 * 64.0;
    double tgt = 0.05 * 0.05;
    while (v > tgt) { eps_list[ne++] = (float)v; v *= 0.25; }
    eps_list[ne++] = (float)tgt;   // ne == 12
  }

  prep_kernel<<<4096, 256, 0, stream>>>(x, y, w1, w2);

  dim3 gg(MM / 128, NN / 128, NB);
  cost_kernel<<<gg, 256, 0, stream>>>(x, y, xn, yn, Cxy);
  cost_kernel<<<gg, 256, 0, stream>>>(x, x, xn, xn, Cxx);
  cost_kernel<<<gg, 256, 0, stream>>>(y, y, yn, yn, Cyy);

  dim3 tg(256, NB, 3);          // z: 0=Cxy(all 256 tiles), 1/2=Cxx/Cyy(tri 136)
  dim3 mg(NN / 256, NB, 4);     // z: potential

  auto launch_iter = [&](float eps, float alpha, float beta, float gscale,
                         int in, int outsel) {
    float inv = 1.0f / eps;
    hprep_kernel<<<64, 256, 0, stream>>>(fab(in), gba(in), faa(in), gbb(in),
                                         gscale * inv);
    TileArgs T0 = {Cxy, h0, h1, pfab, pgba, 0};
    TileArgs T1 = {Cxx, h2, h2, pfaa, pfaa, 1};
    TileArgs T2 = {Cyy, h3, h3, pgbb, pgbb, 1};
    tile_pass<<<tg, 256, 0, stream>>>(T0, T1, T2, inv);
    MergeArgs M0 = {pfab, fab(in), fab(outsel)};
    MergeArgs M1 = {pgba, gba(in), gba(outsel)};
    MergeArgs M2 = {pfaa, faa(in), faa(outsel)};
    MergeArgs M3 = {pgbb, gbb(in), gbb(outsel)};
    merge4<<<mg, 256, 0, stream>>>(M0, M1, M2, M3, eps, alpha, beta);
  };

  // init at eps0: gscale=0 -> h = base log-weights; alpha=0 -> no carry read.
  launch_iter(eps_list[0], 0.f, 1.f, 0.f, 0, 0);

  // scan over the full eps list with 0.5-averaging (Jacobi, banks 0/1)
  int cur = 0;
  for (int k = 0; k < ne; ++k) {
    int nxt = 1 - cur;
    launch_iter(eps_list[k], 0.5f, 0.5f, 1.f, cur, nxt);
    cur = nxt;
  }

  // final extrapolation at eps = blur^p (no averaging) -> bank 2
  launch_iter(eps_list[ne - 1], 0.f, 1.f, 1.f, cur, 2);

  loss_kernel<<<1, 256, 0, stream>>>(w1, w2, out);
}

// Round 8
// 818.751 us; speedup vs baseline: 1.3572x; 1.3572x over previous
//
#include <hip/hip_runtime.h>

#define NB 8
#define NN 2048
#define MM 2048
#define DD 64
#define NMAT ((size_t)NN * (size_t)MM)
#define NCHK 16
#define TS 128

// uint16 fixed-point encoding of C (verified exact: rounds 5/6/7 absmax 0.0)
#define CSCALE 320.0f
#define CDEC   (1.0f / CSCALE)

// ---------------------------------------------------------------------------
// Static device scratch. Three u16 cost slabs (201 MB); per-iteration reads
// touch only 135 MB (Cxy full + upper triangles of Cxx/Cyy) — ONCE now.
// ---------------------------------------------------------------------------
__device__ unsigned short g_C[3 * NB * NMAT];   // Cxy|Cxx|Cyy
// potential banks: [0]/[1] = carry double-buffer, [2] = final
__device__ float g_fab[3][NB * NN], g_gba[3][NB * NN];
__device__ float g_faa[3][NB * NN], g_gbb[3][NB * NN];
__device__ float g_alog[NB * NN], g_blog[NB * NN];
__device__ float g_xn[NB * NN], g_yn[NB * NN];
__device__ float g_h0[NB * MM], g_h1[NB * NN], g_h2[NB * NN], g_h3[NB * MM];
// chunked softmin partials (m,s): [b][chunk][row]
__device__ float2 g_pfab[NB * NCHK * NN];
__device__ float2 g_pgba[NB * NCHK * NN];
__device__ float2 g_pfaa[NB * NCHK * NN];
__device__ float2 g_pgbb[NB * NCHK * NN];

// ---------------------------------------------------------------------------
// prep: a_log/b_log = log(w), xn/yn = 0.5*||row||^2 (one row per wave)
// ---------------------------------------------------------------------------
__global__ __launch_bounds__(256) void prep_kernel(
    const float* __restrict__ x, const float* __restrict__ y,
    const float* __restrict__ w1, const float* __restrict__ w2)
{
  int gid = blockIdx.x * 256 + threadIdx.x;
  if (gid < NB * NN) {
    g_alog[gid] = logf(w1[gid]);
    g_blog[gid] = logf(w2[gid]);
  }
  int lane = threadIdx.x & 63;
  int row = blockIdx.x * 4 + (threadIdx.x >> 6);   // grid 4096 -> rows 0..16383
  float xv = x[(size_t)row * DD + lane];
  float yv = y[(size_t)row * DD + lane];
  float sx = xv * xv;
  float sy = yv * yv;
#pragma unroll
  for (int off = 32; off > 0; off >>= 1) {
    sx += __shfl_down(sx, off);
    sy += __shfl_down(sy, off);
  }
  if (lane == 0) {
    g_xn[row] = 0.5f * sx;
    g_yn[row] = 0.5f * sy;
  }
}

// ---------------------------------------------------------------------------
// cost GEMM: C[b][i][j] = max(xn_i + yn_j - x_i . y_j, 0), uint16 out.
// (verified rounds 5-7; unchanged)
// ---------------------------------------------------------------------------
__global__ __launch_bounds__(256) void cost_kernel(
    const float* __restrict__ X, const float* __restrict__ Y,
    const float* __restrict__ xn, const float* __restrict__ yn,
    unsigned short* __restrict__ C)
{
  __shared__ float Xs[32 * 128];
  __shared__ float Ys[32 * 128];
  const int b = blockIdx.z;
  const int i0 = blockIdx.y * 128;
  const int j0 = blockIdx.x * 128;
  const int t = threadIdx.x;
  const float* xb = X + (size_t)b * NN * DD;
  const float* yb = Y + (size_t)b * MM * DD;
  const int tx = t & 15, ty = t >> 4;

  float acc[8][8];
#pragma unroll
  for (int r = 0; r < 8; ++r)
#pragma unroll
    for (int c = 0; c < 8; ++c) acc[r][c] = 0.f;

  for (int kk = 0; kk < 64; kk += 32) {
    if (kk) __syncthreads();
#pragma unroll
    for (int p = 0; p < 4; ++p) {
      int f = p * 256 + t;
      int r = f >> 3;
      int k4 = (f & 7) << 2;
      float4 vx = ((const float4*)(xb + (size_t)(i0 + r) * DD))[(kk >> 2) + (f & 7)];
      int rs = r ^ k4;
      Xs[(k4 + 0) * 128 + rs] = vx.x;
      Xs[(k4 + 1) * 128 + rs] = vx.y;
      Xs[(k4 + 2) * 128 + rs] = vx.z;
      Xs[(k4 + 3) * 128 + rs] = vx.w;
      float4 vy = ((const float4*)(yb + (size_t)(j0 + r) * DD))[(kk >> 2) + (f & 7)];
      Ys[(k4 + 0) * 128 + rs] = vy.x;
      Ys[(k4 + 1) * 128 + rs] = vy.y;
      Ys[(k4 + 2) * 128 + rs] = vy.z;
      Ys[(k4 + 3) * 128 + rs] = vy.w;
    }
    __syncthreads();

#pragma unroll 4
    for (int k = 0; k < 32; ++k) {
      int s = k & 28;
      float a[8], bb[8];
      *(float4*)&a[0]  = *(const float4*)&Xs[k * 128 + ((ty * 8) ^ s)];
      *(float4*)&a[4]  = *(const float4*)&Xs[k * 128 + ((ty * 8 + 4) ^ s)];
      *(float4*)&bb[0] = *(const float4*)&Ys[k * 128 + ((tx * 8) ^ s)];
      *(float4*)&bb[4] = *(const float4*)&Ys[k * 128 + ((tx * 8 + 4) ^ s)];
#pragma unroll
      for (int r = 0; r < 8; ++r)
#pragma unroll
        for (int c = 0; c < 8; ++c)
          acc[r][c] = fmaf(a[r], bb[c], acc[r][c]);
    }
  }

  float xr[8], yc[8];
#pragma unroll
  for (int r = 0; r < 8; ++r) xr[r] = xn[b * NN + i0 + ty * 8 + r];
#pragma unroll
  for (int c = 0; c < 8; ++c) yc[c] = yn[b * MM + j0 + tx * 8 + c];

#pragma unroll
  for (int r = 0; r < 8; ++r) {
    unsigned short* crow = C + (size_t)b * NMAT
                         + (size_t)(i0 + ty * 8 + r) * MM + j0 + tx * 8;
    unsigned int u[8];
#pragma unroll
    for (int c = 0; c < 8; ++c) {
      float cv = fmaxf(xr[r] + yc[c] - acc[r][c], 0.f);
      u[c] = __float2uint_rn(fminf(cv * CSCALE, 65535.f));
    }
    uint4 ow;
    ow.x = u[0] | (u[1] << 16);
    ow.y = u[2] | (u[3] << 16);
    ow.z = u[4] | (u[5] << 16);
    ow.w = u[6] | (u[7] << 16);
    *(uint4*)crow = ow;
  }
}

// ---------------------------------------------------------------------------
// h-vector prep — used ONCE for the init step (gs = 0); subsequent h's are
// written by merge4.  h0 = blog + gs*gba ; h1 = alog + gs*fab
//                     h2 = alog + gs*faa ; h3 = blog + gs*gbb
// ---------------------------------------------------------------------------
__global__ __launch_bounds__(256) void hprep_kernel(
    const float* __restrict__ fab_in, const float* __restrict__ gba_in,
    const float* __restrict__ faa_in, const float* __restrict__ gbb_in,
    float gs)
{
  int i = blockIdx.x * 256 + threadIdx.x;   // grid 64 -> 16384
  g_h0[i] = fmaf(gs, gba_in[i], g_blog[i]);
  g_h1[i] = fmaf(gs, fab_in[i], g_alog[i]);
  g_h2[i] = fmaf(gs, faa_in[i], g_alog[i]);
  g_h3[i] = fmaf(gs, gbb_in[i], g_blog[i]);
}

// ---------------------------------------------------------------------------
// Unified tile-partial softmin pass (round-7 verified structure), now with
// the tile held in REGISTERS (8 x uint4 per thread) — no phase-B global
// re-read. Row-dir and col-dir (m,s) partials, two-phase max-then-sum,
// LDS cross-thread reduction. Sym slabs: upper-triangle tiles only.
// ---------------------------------------------------------------------------
struct TileArgs {
  const unsigned short* C;
  const float* hrow;
  const float* hcol;
  float2* prow;   // [b][chunk][row]
  float2* pcol;
  int sym;        // 1 => triangular tile enumeration (136 tiles)
};

__global__ __launch_bounds__(256) void tile_pass(
    TileArgs T0, TileArgs T1, TileArgs T2, float inv_eps)
{
  TileArgs A = (blockIdx.z == 0) ? T0 : (blockIdx.z == 1) ? T1 : T2;
  int I, J;
  if (A.sym) {
    if (blockIdx.x >= 136) return;
    int rem = blockIdx.x, ii = 0;
    while (rem >= NCHK - ii) { rem -= NCHK - ii; ++ii; }   // uniform, <=16 iters
    I = ii; J = ii + rem;                                  // I <= J
  } else {
    I = blockIdx.x >> 4;
    J = blockIdx.x & 15;
  }
  const int b = blockIdx.y;
  const int t = threadIdx.x;
  const int ctr = t & 15;   // col-group: tile cols ctr*8 .. +7
  const int rtr = t >> 4;   // row-group: tile rows rtr*8 .. +7
  const float csneg = -inv_eps * CDEC;

  const unsigned short* Cb = A.C + (size_t)b * NMAT
                           + (size_t)(I * TS) * MM + J * TS;

  float hr[8], hc[8];
  {
    const float* hrp = A.hrow + (size_t)b * MM + J * TS + ctr * 8;
    const float* hcp = A.hcol + (size_t)b * MM + I * TS + rtr * 8;
#pragma unroll
    for (int k = 0; k < 8; ++k) { hr[k] = hrp[k]; hc[k] = hcp[k]; }
  }

  // tile chunk -> registers (single global read)
  uint4 cu[8];
#pragma unroll
  for (int r8 = 0; r8 < 8; ++r8)
    cu[r8] = *(const uint4*)(Cb + (size_t)(rtr * 8 + r8) * MM + ctr * 8);

  __shared__ float redR[TS][17], redC[TS][17];   // +1 pad vs bank conflicts
  __shared__ float rowM[TS], colM[TS];

  // ---- phase A: maxes (unpack from registers) ----
  float rm[8], cm[8];
#pragma unroll
  for (int k = 0; k < 8; ++k) { rm[k] = -3.0e38f; cm[k] = -3.0e38f; }
#pragma unroll
  for (int r8 = 0; r8 < 8; ++r8) {
    float base[8];
    base[0] = (float)(cu[r8].x & 0xffff) * csneg;
    base[1] = (float)(cu[r8].x >> 16)    * csneg;
    base[2] = (float)(cu[r8].y & 0xffff) * csneg;
    base[3] = (float)(cu[r8].y >> 16)    * csneg;
    base[4] = (float)(cu[r8].z & 0xffff) * csneg;
    base[5] = (float)(cu[r8].z >> 16)    * csneg;
    base[6] = (float)(cu[r8].w & 0xffff) * csneg;
    base[7] = (float)(cu[r8].w >> 16)    * csneg;
#pragma unroll
    for (int c8 = 0; c8 < 8; ++c8) {
      rm[r8] = fmaxf(rm[r8], hr[c8] + base[c8]);
      cm[c8] = fmaxf(cm[c8], hc[r8] + base[c8]);
    }
  }
#pragma unroll
  for (int r8 = 0; r8 < 8; ++r8) redR[rtr * 8 + r8][ctr] = rm[r8];
#pragma unroll
  for (int c8 = 0; c8 < 8; ++c8) redC[ctr * 8 + c8][rtr] = cm[c8];
  __syncthreads();
  if (t < TS) {
    float m = redR[t][0];
#pragma unroll
    for (int k = 1; k < 16; ++k) m = fmaxf(m, redR[t][k]);
    rowM[t] = m;
  } else {
    int tt = t - TS;
    float m = redC[tt][0];
#pragma unroll
    for (int k = 1; k < 16; ++k) m = fmaxf(m, redC[tt][k]);
    colM[tt] = m;
  }
  __syncthreads();

  float rmv[8], cmv[8];
#pragma unroll
  for (int k = 0; k < 8; ++k) {
    rmv[k] = rowM[rtr * 8 + k];
    cmv[k] = colM[ctr * 8 + k];
  }

  // ---- phase B: sums (unpack same registers again — no global re-read) ----
  float rs[8], cs[8];
#pragma unroll
  for (int k = 0; k < 8; ++k) { rs[k] = 0.f; cs[k] = 0.f; }
#pragma unroll
  for (int r8 = 0; r8 < 8; ++r8) {
    float base[8];
    base[0] = (float)(cu[r8].x & 0xffff) * csneg;
    base[1] = (float)(cu[r8].x >> 16)    * csneg;
    base[2] = (float)(cu[r8].y & 0xffff) * csneg;
    base[3] = (float)(cu[r8].y >> 16)    * csneg;
    base[4] = (float)(cu[r8].z & 0xffff) * csneg;
    base[5] = (float)(cu[r8].z >> 16)    * csneg;
    base[6] = (float)(cu[r8].w & 0xffff) * csneg;
    base[7] = (float)(cu[r8].w >> 16)    * csneg;
#pragma unroll
    for (int c8 = 0; c8 < 8; ++c8) {
      rs[r8] += __expf(hr[c8] + base[c8] - rmv[r8]);
      cs[c8] += __expf(hc[r8] + base[c8] - cmv[c8]);
    }
  }
#pragma unroll
  for (int r8 = 0; r8 < 8; ++r8) redR[rtr * 8 + r8][ctr] = rs[r8];
#pragma unroll
  for (int c8 = 0; c8 < 8; ++c8) redC[ctr * 8 + c8][rtr] = cs[c8];
  __syncthreads();
  if (t < TS) {
    float s = 0.f;
#pragma unroll
    for (int k = 0; k < 16; ++k) s += redR[t][k];
    A.prow[((size_t)b * NCHK + J) * NN + I * TS + t] = make_float2(rowM[t], s);
  } else {
    int tt = t - TS;
    if (!(A.sym && I == J)) {   // diagonal col-dir duplicates row-dir: skip
      float s = 0.f;
#pragma unroll
      for (int k = 0; k < 16; ++k) s += redC[tt][k];
      A.pcol[((size_t)b * NCHK + I) * NN + J * TS + tt] = make_float2(colM[tt], s);
    }
  }
}

// ---------------------------------------------------------------------------
// merge 16 chunk-partials per row -> softmin value + Jacobi update,
// AND write the next iteration's h vector (fused hprep).
// ---------------------------------------------------------------------------
struct MergeArgs {
  const float2* part;
  const float* fold;
  float* fout;
  const float* hbase;   // alog or blog
  float* hout;          // h vector consumed by the next tile_pass
};

__global__ __launch_bounds__(256) void merge4(
    MergeArgs M0, MergeArgs M1, MergeArgs M2, MergeArgs M3,
    float eps, float alpha, float beta, float nextgs)
{
  MergeArgs A = (blockIdx.z == 0) ? M0 : (blockIdx.z == 1) ? M1
              : (blockIdx.z == 2) ? M2 : M3;
  const int b = blockIdx.y;
  const int i = blockIdx.x * 256 + threadIdx.x;   // grid.x = NN/256
  float2 p[NCHK];
#pragma unroll
  for (int k = 0; k < NCHK; ++k)
    p[k] = A.part[((size_t)b * NCHK + k) * NN + i];
  float M = p[0].x;
#pragma unroll
  for (int k = 1; k < NCHK; ++k) M = fmaxf(M, p[k].x);
  float S = 0.f;
#pragma unroll
  for (int k = 0; k < NCHK; ++k) S += p[k].y * __expf(p[k].x - M);
  float ft = -eps * (M + __logf(S));
  int idx = b * NN + i;
  float fnew = alpha * A.fold[idx] + beta * ft;
  A.fout[idx] = fnew;
  A.hout[idx] = fmaf(nextgs, fnew, A.hbase[idx]);
}

// ---------------------------------------------------------------------------
// loss = mean_b [ sum_i w1*(fabf - faaf) + sum_j w2*(gbaf - gbbf) ]
// ---------------------------------------------------------------------------
__global__ __launch_bounds__(256) void loss_kernel(
    const float* __restrict__ w1, const float* __restrict__ w2,
    float* __restrict__ out)
{
  __shared__ float red[256];
  float acc = 0.f;
  for (int idx = threadIdx.x; idx < NB * NN; idx += 256) {
    acc += w1[idx] * (g_fab[2][idx] - g_faa[2][idx])
         + w2[idx] * (g_gba[2][idx] - g_gbb[2][idx]);
  }
  red[threadIdx.x] = acc;
  __syncthreads();
  for (int s = 128; s > 0; s >>= 1) {
    if (threadIdx.x < s) red[threadIdx.x] += red[threadIdx.x + s];
    __syncthreads();
  }
  if (threadIdx.x == 0) out[0] = red[0] * (1.0f / NB);
}

// ---------------------------------------------------------------------------
extern "C" void kernel_launch(void* const* d_in, const int* in_sizes, int n_in,
                              void* d_out, int out_size, void* d_ws, size_t ws_size,
                              hipStream_t stream)
{
  const float* x = (const float*)d_in[0];
  const float* y = (const float*)d_in[1];
  const float* w1 = (const float*)d_in[2];
  const float* w2 = (const float*)d_in[3];
  float* out = (float*)d_out;

  unsigned short* Cbase;
  hipGetSymbolAddress((void**)&Cbase, HIP_SYMBOL(g_C));
  unsigned short* Cxy = Cbase + 0ull * NB * NMAT;
  unsigned short* Cxx = Cbase + 1ull * NB * NMAT;
  unsigned short* Cyy = Cbase + 2ull * NB * NMAT;
  float *xn, *yn, *h0, *h1, *h2, *h3, *fabp, *gbap, *faap, *gbbp, *alog, *blog;
  float2 *pfab, *pgba, *pfaa, *pgbb;
  hipGetSymbolAddress((void**)&xn, HIP_SYMBOL(g_xn));
  hipGetSymbolAddress((void**)&yn, HIP_SYMBOL(g_yn));
  hipGetSymbolAddress((void**)&h0, HIP_SYMBOL(g_h0));
  hipGetSymbolAddress((void**)&h1, HIP_SYMBOL(g_h1));
  hipGetSymbolAddress((void**)&h2, HIP_SYMBOL(g_h2));
  hipGetSymbolAddress((void**)&h3, HIP_SYMBOL(g_h3));
  hipGetSymbolAddress((void**)&fabp, HIP_SYMBOL(g_fab));
  hipGetSymbolAddress((void**)&gbap, HIP_SYMBOL(g_gba));
  hipGetSymbolAddress((void**)&faap, HIP_SYMBOL(g_faa));
  hipGetSymbolAddress((void**)&gbbp, HIP_SYMBOL(g_gbb));
  hipGetSymbolAddress((void**)&alog, HIP_SYMBOL(g_alog));
  hipGetSymbolAddress((void**)&blog, HIP_SYMBOL(g_blog));
  hipGetSymbolAddress((void**)&pfab, HIP_SYMBOL(g_pfab));
  hipGetSymbolAddress((void**)&pgba, HIP_SYMBOL(g_pgba));
  hipGetSymbolAddress((void**)&pfaa, HIP_SYMBOL(g_pfaa));
  hipGetSymbolAddress((void**)&pgbb, HIP_SYMBOL(g_pgbb));

  auto fab = [&](int s) { return fabp + (size_t)s * NB * NN; };
  auto gba = [&](int s) { return gbap + (size_t)s * NB * NN; };
  auto faa = [&](int s) { return faap + (size_t)s * NB * NN; };
  auto gbb = [&](int s) { return gbbp + (size_t)s * NB * NN; };

  // eps schedule (matches the Python double loop, then cast to fp32)
  float eps_list[32];
  int ne = 0;
  {
    double v = 64.0 * 64.0;
    double tgt = 0.05 * 0.05;
    while (v > tgt) { eps_list[ne++] = (float)v; v *= 0.25; }
    eps_list[ne++] = (float)tgt;   // ne == 12
  }

  prep_kernel<<<4096, 256, 0, stream>>>(x, y, w1, w2);

  dim3 gg(MM / 128, NN / 128, NB);
  cost_kernel<<<gg, 256, 0, stream>>>(x, y, xn, yn, Cxy);
  cost_kernel<<<gg, 256, 0, stream>>>(x, x, xn, xn, Cxx);
  cost_kernel<<<gg, 256, 0, stream>>>(y, y, yn, yn, Cyy);

  dim3 tg(256, NB, 3);          // z: 0=Cxy(256 tiles), 1/2=Cxx/Cyy(tri 136)
  dim3 mg(NN / 256, NB, 4);     // z: potential

  // one iteration: tile_pass (h already in place) + merge4 (writes next h)
  auto launch_iter = [&](float eps, float alpha, float beta, float nextgs,
                         int in, int outsel) {
    float inv = 1.0f / eps;
    TileArgs T0 = {Cxy, h0, h1, pfab, pgba, 0};
    TileArgs T1 = {Cxx, h2, h2, pfaa, pfaa, 1};
    TileArgs T2 = {Cyy, h3, h3, pgbb, pgbb, 1};
    tile_pass<<<tg, 256, 0, stream>>>(T0, T1, T2, inv);
    MergeArgs M0 = {pfab, fab(in), fab(outsel), alog, h1};
    MergeArgs M1 = {pgba, gba(in), gba(outsel), blog, h0};
    MergeArgs M2 = {pfaa, faa(in), faa(outsel), alog, h2};
    MergeArgs M3 = {pgbb, gbb(in), gbb(outsel), blog, h3};
    merge4<<<mg, 256, 0, stream>>>(M0, M1, M2, M3, eps, alpha, beta, nextgs);
  };

  // init at eps0: h = base log-weights (gs=0), alpha=0 -> no carry read;
  // its merge writes h for scan step k=0.
  hprep_kernel<<<64, 256, 0, stream>>>(fab(0), gba(0), faa(0), gbb(0), 0.f);
  launch_iter(eps_list[0], 0.f, 1.f, 1.0f / eps_list[0], 0, 0);

  // scan over the full eps list with 0.5-averaging (Jacobi, banks 0/1);
  // each merge writes h for the NEXT step (k+1, or the final extrapolation).
  int cur = 0;
  for (int k = 0; k < ne; ++k) {
    int nxt = 1 - cur;
    float nextgs = 1.0f / ((k < ne - 1) ? eps_list[k + 1] : eps_list[ne - 1]);
    launch_iter(eps_list[k], 0.5f, 0.5f, nextgs, cur, nxt);
    cur = nxt;
  }

  // final extrapolation at eps = blur^p (no averaging) -> bank 2
  launch_iter(eps_list[ne - 1], 0.f, 1.f, 0.f, cur, 2);

  loss_kernel<<<1, 256, 0, stream>>>(w1, w2, out);
}

// Round 9
// 765.040 us; speedup vs baseline: 1.4525x; 1.0702x over previous
//
#include <hip/hip_runtime.h>

#define NB 8
#define NN 2048
#define MM 2048
#define DD 64
#define NMAT ((size_t)NN * (size_t)MM)
#define NCHK 16
#define TS 128

// uint16 fixed-point encoding of C (verified exact: rounds 5-8 absmax 0.0)
#define CSCALE 320.0f
#define CDEC   (1.0f / CSCALE)

typedef _Float16 half_t;
typedef __attribute__((ext_vector_type(8))) _Float16 f16x8;
typedef __attribute__((ext_vector_type(4))) float f32x4;

// ---------------------------------------------------------------------------
// Static device scratch. Three u16 cost slabs; sym slabs hold valid data only
// in upper-triangle 128-chunks (all tile_pass ever reads).
// ---------------------------------------------------------------------------
__device__ unsigned short g_C[3 * NB * NMAT];   // Cxy|Cxx|Cyy
__device__ half_t g_xh[NB * NN * DD];           // fp16 copies for MFMA
__device__ half_t g_yh[NB * MM * DD];
// potential banks: [0]/[1] = carry double-buffer, [2] = final
__device__ float g_fab[3][NB * NN], g_gba[3][NB * NN];
__device__ float g_faa[3][NB * NN], g_gbb[3][NB * NN];
__device__ float g_alog[NB * NN], g_blog[NB * NN];
__device__ float g_xn[NB * NN], g_yn[NB * NN];
__device__ float g_h0[NB * MM], g_h1[NB * NN], g_h2[NB * NN], g_h3[NB * MM];
// chunked softmin partials (m,s): [b][chunk][row]
__device__ float2 g_pfab[NB * NCHK * NN];
__device__ float2 g_pgba[NB * NCHK * NN];
__device__ float2 g_pfaa[NB * NCHK * NN];
__device__ float2 g_pgbb[NB * NCHK * NN];

// ---------------------------------------------------------------------------
// prep: a_log/b_log = log(w), xn/yn = 0.5*||row||^2, and fp16 copies of x,y.
// ---------------------------------------------------------------------------
__global__ __launch_bounds__(256) void prep_kernel(
    const float* __restrict__ x, const float* __restrict__ y,
    const float* __restrict__ w1, const float* __restrict__ w2)
{
  int gid = blockIdx.x * 256 + threadIdx.x;
  if (gid < NB * NN) {
    g_alog[gid] = logf(w1[gid]);
    g_blog[gid] = logf(w2[gid]);
  }
  int lane = threadIdx.x & 63;
  int row = blockIdx.x * 4 + (threadIdx.x >> 6);   // grid 4096 -> rows 0..16383
  float xv = x[(size_t)row * DD + lane];
  float yv = y[(size_t)row * DD + lane];
  g_xh[(size_t)row * DD + lane] = (half_t)xv;
  g_yh[(size_t)row * DD + lane] = (half_t)yv;
  float sx = xv * xv;
  float sy = yv * yv;
#pragma unroll
  for (int off = 32; off > 0; off >>= 1) {
    sx += __shfl_down(sx, off);
    sy += __shfl_down(sy, off);
  }
  if (lane == 0) {
    g_xn[row] = 0.5f * sx;
    g_yn[row] = 0.5f * sy;
  }
}

// ---------------------------------------------------------------------------
// MFMA cost build: C[b][i][j] = max(xn_i + yn_j - x_i . y_j, 0) -> u16.
// One dispatch, all 3 slabs: z = slab*8 + b. 64x64 block = 4 waves, each wave
// 16 rows x 64 cols via 4 x mfma_f32_16x16x32_f16 (K=64 in 2 steps).
// Fragment layouts (HW-verified): A[m=lane&15][k=quad*8+j];
// B[k][n=lane&15] same per-lane gather; D col=lane&15, row=quad*4+reg.
// Sym slabs (Cxx/Cyy): only blocks whose 128-chunk is upper-triangle.
// ---------------------------------------------------------------------------
__global__ __launch_bounds__(256) void cost_mfma()
{
  const int slab = blockIdx.z >> 3;
  const int b = blockIdx.z & 7;
  const int bi = blockIdx.y, bj = blockIdx.x;
  if (slab && ((bj >> 1) < (bi >> 1))) return;   // unread lower 128-chunks

  const half_t* Ah = (slab == 2) ? g_yh : g_xh;
  const half_t* Bh = (slab == 0) ? g_yh : ((slab == 1) ? g_xh : g_yh);
  const float* na = (slab == 2) ? g_yn : g_xn;
  const float* nbp = (slab == 0) ? g_yn : ((slab == 1) ? g_xn : g_yn);
  unsigned short* Cout = g_C + (size_t)slab * NB * NMAT + (size_t)b * NMAT;

  const int t = threadIdx.x;
  const int w = t >> 6, lane = t & 63;
  const int m = lane & 15, quad = lane >> 4;
  const int i0 = bi * 64, j0 = bj * 64;

  const half_t* Ab = Ah + ((size_t)b * NN + i0 + 16 * w + m) * DD + quad * 8;
  const half_t* Bb = Bh + ((size_t)b * MM + j0 + m) * DD + quad * 8;

  f32x4 acc[4];
#pragma unroll
  for (int c = 0; c < 4; ++c) acc[c] = (f32x4){0.f, 0.f, 0.f, 0.f};

#pragma unroll
  for (int s = 0; s < 2; ++s) {
    f16x8 a = *(const f16x8*)(Ab + s * 32);
#pragma unroll
    for (int c = 0; c < 4; ++c) {
      f16x8 bf = *(const f16x8*)(Bb + (size_t)(16 * c) * DD + s * 32);
      acc[c] = __builtin_amdgcn_mfma_f32_16x16x32_f16(a, bf, acc[c], 0, 0, 0);
    }
  }

  __shared__ unsigned short tile[64 * 64];
  float xr[4];
#pragma unroll
  for (int r = 0; r < 4; ++r) xr[r] = na[b * NN + i0 + 16 * w + quad * 4 + r];
#pragma unroll
  for (int c = 0; c < 4; ++c) {
    float yv = nbp[b * MM + j0 + 16 * c + m];
#pragma unroll
    for (int r = 0; r < 4; ++r) {
      float cv = fmaxf(xr[r] + yv - acc[c][r], 0.f);
      unsigned int u = __float2uint_rn(fminf(cv * CSCALE, 65535.f));
      tile[(16 * w + quad * 4 + r) * 64 + 16 * c + m] = (unsigned short)u;
    }
  }
  __syncthreads();

  const uint4* tl = (const uint4*)tile;   // 512 uint4 in the tile
#pragma unroll
  for (int p = 0; p < 2; ++p) {
    int u = p * 256 + t;
    int row = u >> 3, c8 = (u & 7) * 8;
    *(uint4*)(Cout + (size_t)(i0 + row) * MM + j0 + c8) = tl[u];
  }
}

// ---------------------------------------------------------------------------
// h-vector prep — used ONCE for the init step (gs = 0); subsequent h's are
// written by merge4.
// ---------------------------------------------------------------------------
__global__ __launch_bounds__(256) void hprep_kernel(
    const float* __restrict__ fab_in, const float* __restrict__ gba_in,
    const float* __restrict__ faa_in, const float* __restrict__ gbb_in,
    float gs)
{
  int i = blockIdx.x * 256 + threadIdx.x;   // grid 64 -> 16384
  g_h0[i] = fmaf(gs, gba_in[i], g_blog[i]);
  g_h1[i] = fmaf(gs, fab_in[i], g_alog[i]);
  g_h2[i] = fmaf(gs, faa_in[i], g_alog[i]);
  g_h3[i] = fmaf(gs, gbb_in[i], g_blog[i]);
}

// ---------------------------------------------------------------------------
// Unified tile-partial softmin pass (verified round 8, UNCHANGED).
// ---------------------------------------------------------------------------
struct TileArgs {
  const unsigned short* C;
  const float* hrow;
  const float* hcol;
  float2* prow;   // [b][chunk][row]
  float2* pcol;
  int sym;        // 1 => triangular tile enumeration (136 tiles)
};

__global__ __launch_bounds__(256) void tile_pass(
    TileArgs T0, TileArgs T1, TileArgs T2, float inv_eps)
{
  TileArgs A = (blockIdx.z == 0) ? T0 : (blockIdx.z == 1) ? T1 : T2;
  int I, J;
  if (A.sym) {
    if (blockIdx.x >= 136) return;
    int rem = blockIdx.x, ii = 0;
    while (rem >= NCHK - ii) { rem -= NCHK - ii; ++ii; }   // uniform, <=16 iters
    I = ii; J = ii + rem;                                  // I <= J
  } else {
    I = blockIdx.x >> 4;
    J = blockIdx.x & 15;
  }
  const int b = blockIdx.y;
  const int t = threadIdx.x;
  const int ctr = t & 15;   // col-group: tile cols ctr*8 .. +7
  const int rtr = t >> 4;   // row-group: tile rows rtr*8 .. +7
  const float csneg = -inv_eps * CDEC;

  const unsigned short* Cb = A.C + (size_t)b * NMAT
                           + (size_t)(I * TS) * MM + J * TS;

  float hr[8], hc[8];
  {
    const float* hrp = A.hrow + (size_t)b * MM + J * TS + ctr * 8;
    const float* hcp = A.hcol + (size_t)b * MM + I * TS + rtr * 8;
#pragma unroll
    for (int k = 0; k < 8; ++k) { hr[k] = hrp[k]; hc[k] = hcp[k]; }
  }

  // tile chunk -> registers (single global read)
  uint4 cu[8];
#pragma unroll
  for (int r8 = 0; r8 < 8; ++r8)
    cu[r8] = *(const uint4*)(Cb + (size_t)(rtr * 8 + r8) * MM + ctr * 8);

  __shared__ float redR[TS][17], redC[TS][17];   // +1 pad vs bank conflicts
  __shared__ float rowM[TS], colM[TS];

  // ---- phase A: maxes (unpack from registers) ----
  float rm[8], cm[8];
#pragma unroll
  for (int k = 0; k < 8; ++k) { rm[k] = -3.0e38f; cm[k] = -3.0e38f; }
#pragma unroll
  for (int r8 = 0; r8 < 8; ++r8) {
    float base[8];
    base[0] = (float)(cu[r8].x & 0xffff) * csneg;
    base[1] = (float)(cu[r8].x >> 16)    * csneg;
    base[2] = (float)(cu[r8].y & 0xffff) * csneg;
    base[3] = (float)(cu[r8].y >> 16)    * csneg;
    base[4] = (float)(cu[r8].z & 0xffff) * csneg;
    base[5] = (float)(cu[r8].z >> 16)    * csneg;
    base[6] = (float)(cu[r8].w & 0xffff) * csneg;
    base[7] = (float)(cu[r8].w >> 16)    * csneg;
#pragma unroll
    for (int c8 = 0; c8 < 8; ++c8) {
      rm[r8] = fmaxf(rm[r8], hr[c8] + base[c8]);
      cm[c8] = fmaxf(cm[c8], hc[r8] + base[c8]);
    }
  }
#pragma unroll
  for (int r8 = 0; r8 < 8; ++r8) redR[rtr * 8 + r8][ctr] = rm[r8];
#pragma unroll
  for (int c8 = 0; c8 < 8; ++c8) redC[ctr * 8 + c8][rtr] = cm[c8];
  __syncthreads();
  if (t < TS) {
    float m = redR[t][0];
#pragma unroll
    for (int k = 1; k < 16; ++k) m = fmaxf(m, redR[t][k]);
    rowM[t] = m;
  } else {
    int tt = t - TS;
    float m = redC[tt][0];
#pragma unroll
    for (int k = 1; k < 16; ++k) m = fmaxf(m, redC[tt][k]);
    colM[tt] = m;
  }
  __syncthreads();

  float rmv[8], cmv[8];
#pragma unroll
  for (int k = 0; k < 8; ++k) {
    rmv[k] = rowM[rtr * 8 + k];
    cmv[k] = colM[ctr * 8 + k];
  }

  // ---- phase B: sums (unpack same registers again — no global re-read) ----
  float rs[8], cs[8];
#pragma unroll
  for (int k = 0; k < 8; ++k) { rs[k] = 0.f; cs[k] = 0.f; }
#pragma unroll
  for (int r8 = 0; r8 < 8; ++r8) {
    float base[8];
    base[0] = (float)(cu[r8].x & 0xffff) * csneg;
    base[1] = (float)(cu[r8].x >> 16)    * csneg;
    base[2] = (float)(cu[r8].y & 0xffff) * csneg;
    base[3] = (float)(cu[r8].y >> 16)    * csneg;
    base[4] = (float)(cu[r8].z & 0xffff) * csneg;
    base[5] = (float)(cu[r8].z >> 16)    * csneg;
    base[6] = (float)(cu[r8].w & 0xffff) * csneg;
    base[7] = (float)(cu[r8].w >> 16)    * csneg;
#pragma unroll
    for (int c8 = 0; c8 < 8; ++c8) {
      rs[r8] += __expf(hr[c8] + base[c8] - rmv[r8]);
      cs[c8] += __expf(hc[r8] + base[c8] - cmv[c8]);
    }
  }
#pragma unroll
  for (int r8 = 0; r8 < 8; ++r8) redR[rtr * 8 + r8][ctr] = rs[r8];
#pragma unroll
  for (int c8 = 0; c8 < 8; ++c8) redC[ctr * 8 + c8][rtr] = cs[c8];
  __syncthreads();
  if (t < TS) {
    float s = 0.f;
#pragma unroll
    for (int k = 0; k < 16; ++k) s += redR[t][k];
    A.prow[((size_t)b * NCHK + J) * NN + I * TS + t] = make_float2(rowM[t], s);
  } else {
    int tt = t - TS;
    if (!(A.sym && I == J)) {   // diagonal col-dir duplicates row-dir: skip
      float s = 0.f;
#pragma unroll
      for (int k = 0; k < 16; ++k) s += redC[tt][k];
      A.pcol[((size_t)b * NCHK + I) * NN + J * TS + tt] = make_float2(colM[tt], s);
    }
  }
}

// ---------------------------------------------------------------------------
// merge 16 chunk-partials per row -> softmin + Jacobi update + next-h write.
// (verified round 8, unchanged)
// ---------------------------------------------------------------------------
struct MergeArgs {
  const float2* part;
  const float* fold;
  float* fout;
  const float* hbase;   // alog or blog
  float* hout;          // h vector consumed by the next tile_pass
};

__global__ __launch_bounds__(256) void merge4(
    MergeArgs M0, MergeArgs M1, MergeArgs M2, MergeArgs M3,
    float eps, float alpha, float beta, float nextgs)
{
  MergeArgs A = (blockIdx.z == 0) ? M0 : (blockIdx.z == 1) ? M1
              : (blockIdx.z == 2) ? M2 : M3;
  const int b = blockIdx.y;
  const int i = blockIdx.x * 256 + threadIdx.x;   // grid.x = NN/256
  float2 p[NCHK];
#pragma unroll
  for (int k = 0; k < NCHK; ++k)
    p[k] = A.part[((size_t)b * NCHK + k) * NN + i];
  float M = p[0].x;
#pragma unroll
  for (int k = 1; k < NCHK; ++k) M = fmaxf(M, p[k].x);
  float S = 0.f;
#pragma unroll
  for (int k = 0; k < NCHK; ++k) S += p[k].y * __expf(p[k].x - M);
  float ft = -eps * (M + __logf(S));
  int idx = b * NN + i;
  float fnew = alpha * A.fold[idx] + beta * ft;
  A.fout[idx] = fnew;
  A.hout[idx] = fmaf(nextgs, fnew, A.hbase[idx]);
}

// ---------------------------------------------------------------------------
// loss = mean_b [ sum_i w1*(fabf - faaf) + sum_j w2*(gbaf - gbbf) ]
// ---------------------------------------------------------------------------
__global__ __launch_bounds__(256) void loss_kernel(
    const float* __restrict__ w1, const float* __restrict__ w2,
    float* __restrict__ out)
{
  __shared__ float red[256];
  float acc = 0.f;
  for (int idx = threadIdx.x; idx < NB * NN; idx += 256) {
    acc += w1[idx] * (g_fab[2][idx] - g_faa[2][idx])
         + w2[idx] * (g_gba[2][idx] - g_gbb[2][idx]);
  }
  red[threadIdx.x] = acc;
  __syncthreads();
  for (int s = 128; s > 0; s >>= 1) {
    if (threadIdx.x < s) red[threadIdx.x] += red[threadIdx.x + s];
    __syncthreads();
  }
  if (threadIdx.x == 0) out[0] = red[0] * (1.0f / NB);
}

// ---------------------------------------------------------------------------
extern "C" void kernel_launch(void* const* d_in, const int* in_sizes, int n_in,
                              void* d_out, int out_size, void* d_ws, size_t ws_size,
                              hipStream_t stream)
{
  const float* x = (const float*)d_in[0];
  const float* y = (const float*)d_in[1];
  const float* w1 = (const float*)d_in[2];
  const float* w2 = (const float*)d_in[3];
  float* out = (float*)d_out;

  unsigned short* Cbase;
  hipGetSymbolAddress((void**)&Cbase, HIP_SYMBOL(g_C));
  unsigned short* Cxy = Cbase + 0ull * NB * NMAT;
  unsigned short* Cxx = Cbase + 1ull * NB * NMAT;
  unsigned short* Cyy = Cbase + 2ull * NB * NMAT;
  float *h0, *h1, *h2, *h3, *fabp, *gbap, *faap, *gbbp, *alog, *blog;
  float2 *pfab, *pgba, *pfaa, *pgbb;
  hipGetSymbolAddress((void**)&h0, HIP_SYMBOL(g_h0));
  hipGetSymbolAddress((void**)&h1, HIP_SYMBOL(g_h1));
  hipGetSymbolAddress((void**)&h2, HIP_SYMBOL(g_h2));
  hipGetSymbolAddress((void**)&h3, HIP_SYMBOL(g_h3));
  hipGetSymbolAddress((void**)&fabp, HIP_SYMBOL(g_fab));
  hipGetSymbolAddress((void**)&gbap, HIP_SYMBOL(g_gba));
  hipGetSymbolAddress((void**)&faap, HIP_SYMBOL(g_faa));
  hipGetSymbolAddress((void**)&gbbp, HIP_SYMBOL(g_gbb));
  hipGetSymbolAddress((void**)&alog, HIP_SYMBOL(g_alog));
  hipGetSymbolAddress((void**)&blog, HIP_SYMBOL(g_blog));
  hipGetSymbolAddress((void**)&pfab, HIP_SYMBOL(g_pfab));
  hipGetSymbolAddress((void**)&pgba, HIP_SYMBOL(g_pgba));
  hipGetSymbolAddress((void**)&pfaa, HIP_SYMBOL(g_pfaa));
  hipGetSymbolAddress((void**)&pgbb, HIP_SYMBOL(g_pgbb));

  auto fab = [&](int s) { return fabp + (size_t)s * NB * NN; };
  auto gba = [&](int s) { return gbap + (size_t)s * NB * NN; };
  auto faa = [&](int s) { return faap + (size_t)s * NB * NN; };
  auto gbb = [&](int s) { return gbbp + (size_t)s * NB * NN; };

  // eps schedule (matches the Python double loop, then cast to fp32)
  float eps_list[32];
  int ne = 0;
  {
    double v = 64.0 * 64.0;
    double tgt = 0.05 * 0.05;
    while (v > tgt) { eps_list[ne++] = (float)v; v *= 0.25; }
    eps_list[ne++] = (float)tgt;   // ne == 12
  }

  prep_kernel<<<4096, 256, 0, stream>>>(x, y, w1, w2);

  // all three cost slabs in one dispatch; sym slabs build upper chunks only
  cost_mfma<<<dim3(32, 32, 24), 256, 0, stream>>>();

  dim3 tg(256, NB, 3);          // z: 0=Cxy(256 tiles), 1/2=Cxx/Cyy(tri 136)
  dim3 mg(NN / 256, NB, 4);     // z: potential

  // one iteration: tile_pass (h already in place) + merge4 (writes next h)
  auto launch_iter = [&](float eps, float alpha, float beta, float nextgs,
                         int in, int outsel) {
    float inv = 1.0f / eps;
    TileArgs T0 = {Cxy, h0, h1, pfab, pgba, 0};
    TileArgs T1 = {Cxx, h2, h2, pfaa, pfaa, 1};
    TileArgs T2 = {Cyy, h3, h3, pgbb, pgbb, 1};
    tile_pass<<<tg, 256, 0, stream>>>(T0, T1, T2, inv);
    MergeArgs M0 = {pfab, fab(in), fab(outsel), alog, h1};
    MergeArgs M1 = {pgba, gba(in), gba(outsel), blog, h0};
    MergeArgs M2 = {pfaa, faa(in), faa(outsel), alog, h2};
    MergeArgs M3 = {pgbb, gbb(in), gbb(outsel), blog, h3};
    merge4<<<mg, 256, 0, stream>>>(M0, M1, M2, M3, eps, alpha, beta, nextgs);
  };

  // init at eps0: h = base log-weights (gs=0), alpha=0 -> no carry read;
  // its merge writes h for scan step k=0.
  hprep_kernel<<<64, 256, 0, stream>>>(fab(0), gba(0), faa(0), gbb(0), 0.f);
  launch_iter(eps_list[0], 0.f, 1.f, 1.0f / eps_list[0], 0, 0);

  // scan over the full eps list with 0.5-averaging (Jacobi, banks 0/1);
  // each merge writes h for the NEXT step (k+1, or the final extrapolation).
  int cur = 0;
  for (int k = 0; k < ne; ++k) {
    int nxt = 1 - cur;
    float nextgs = 1.0f / ((k < ne - 1) ? eps_list[k + 1] : eps_list[ne - 1]);
    launch_iter(eps_list[k], 0.5f, 0.5f, nextgs, cur, nxt);
    cur = nxt;
  }

  // final extrapolation at eps = blur^p (no averaging) -> bank 2
  launch_iter(eps_list[ne - 1], 0.f, 1.f, 0.f, cur, 2);

  loss_kernel<<<1, 256, 0, stream>>>(w1, w2, out);
}

// Round 10
// 711.938 us; speedup vs baseline: 1.5608x; 1.0746x over previous
//
#include <hip/hip_runtime.h>

#define NB 8
#define NN 2048
#define MM 2048
#define DD 64
#define NMAT ((size_t)NN * (size_t)MM)
#define NCHK 16
#define TS 128

// uint16 fixed-point encoding of C (verified exact: rounds 5-9 absmax 0.0)
#define CSCALE 320.0f
#define CDEC   (1.0f / CSCALE)

typedef _Float16 half_t;
typedef __attribute__((ext_vector_type(8))) _Float16 f16x8;
typedef __attribute__((ext_vector_type(4))) float f32x4;

// ---------------------------------------------------------------------------
// Static device scratch. Three u16 cost slabs; sym slabs hold valid data only
// in upper-triangle 128-chunks (all tile_pass ever reads).
// ---------------------------------------------------------------------------
__device__ unsigned short g_C[3 * NB * NMAT];   // Cxy|Cxx|Cyy
__device__ half_t g_xh[NB * NN * DD];           // fp16 copies for MFMA
__device__ half_t g_yh[NB * MM * DD];
// potential banks: [0]/[1] = carry double-buffer, [2] = final
__device__ float g_fab[3][NB * NN], g_gba[3][NB * NN];
__device__ float g_faa[3][NB * NN], g_gbb[3][NB * NN];
__device__ float g_alog[NB * NN], g_blog[NB * NN];
__device__ float g_xn[NB * NN], g_yn[NB * NN];
__device__ float g_h0[NB * MM], g_h1[NB * NN], g_h2[NB * NN], g_h3[NB * MM];
// chunked softmin partials (m,s): [b][chunk][row]
__device__ float2 g_pfab[NB * NCHK * NN];
__device__ float2 g_pgba[NB * NCHK * NN];
__device__ float2 g_pfaa[NB * NCHK * NN];
__device__ float2 g_pgbb[NB * NCHK * NN];

// ---------------------------------------------------------------------------
// prep: a_log/b_log = log(w), xn/yn = 0.5*||row||^2, and fp16 copies of x,y.
// ---------------------------------------------------------------------------
__global__ __launch_bounds__(256) void prep_kernel(
    const float* __restrict__ x, const float* __restrict__ y,
    const float* __restrict__ w1, const float* __restrict__ w2)
{
  int gid = blockIdx.x * 256 + threadIdx.x;
  if (gid < NB * NN) {
    g_alog[gid] = logf(w1[gid]);
    g_blog[gid] = logf(w2[gid]);
  }
  int lane = threadIdx.x & 63;
  int row = blockIdx.x * 4 + (threadIdx.x >> 6);   // grid 4096 -> rows 0..16383
  float xv = x[(size_t)row * DD + lane];
  float yv = y[(size_t)row * DD + lane];
  g_xh[(size_t)row * DD + lane] = (half_t)xv;
  g_yh[(size_t)row * DD + lane] = (half_t)yv;
  float sx = xv * xv;
  float sy = yv * yv;
#pragma unroll
  for (int off = 32; off > 0; off >>= 1) {
    sx += __shfl_down(sx, off);
    sy += __shfl_down(sy, off);
  }
  if (lane == 0) {
    g_xn[row] = 0.5f * sx;
    g_yn[row] = 0.5f * sy;
  }
}

// ---------------------------------------------------------------------------
// MFMA cost build v2: 128x128 tile per block (4 waves; wave w = rows
// 32w..32w+31 as 2 row-groups x 8 col-groups = 16 accs, 32 MFMAs).
// Per-element MFMA sequence identical to the verified round-9 kernel.
// z = slab*8 + b; slab 0 = all 256 tiles, slabs 1/2 = 136 upper-tri tiles.
// Fragment layouts (HW-verified green): A[m=lane&15][k=quad*8+j];
// B same gather on Y rows; D col=16c+(lane&15), row=quad*4+reg.
// ---------------------------------------------------------------------------
__global__ __launch_bounds__(256) void cost_mfma()
{
  const int slab = blockIdx.z >> 3;
  const int b = blockIdx.z & 7;
  int I, J;
  if (slab) {
    if (blockIdx.x >= 136) return;
    int rem = blockIdx.x, ii = 0;
    while (rem >= NCHK - ii) { rem -= NCHK - ii; ++ii; }   // uniform, <=16 iters
    I = ii; J = ii + rem;                                  // I <= J
  } else {
    I = blockIdx.x >> 4;
    J = blockIdx.x & 15;
  }

  const half_t* Ah = (slab == 2) ? g_yh : g_xh;
  const half_t* Bh = (slab == 0) ? g_yh : ((slab == 1) ? g_xh : g_yh);
  const float* na = (slab == 2) ? g_yn : g_xn;
  const float* nbp = (slab == 0) ? g_yn : ((slab == 1) ? g_xn : g_yn);
  unsigned short* Cout = g_C + (size_t)slab * NB * NMAT + (size_t)b * NMAT;

  const int t = threadIdx.x;
  const int w = t >> 6, lane = t & 63;
  const int m = lane & 15, quad = lane >> 4;
  const int i0 = I * TS, j0 = J * TS;

  const half_t* Abase = Ah + ((size_t)b * NN + i0 + 32 * w + m) * DD + quad * 8;
  const half_t* Bbase = Bh + ((size_t)b * MM + j0 + m) * DD + quad * 8;

  f32x4 acc[2][8];
#pragma unroll
  for (int g = 0; g < 2; ++g)
#pragma unroll
    for (int c = 0; c < 8; ++c) acc[g][c] = (f32x4){0.f, 0.f, 0.f, 0.f};

#pragma unroll
  for (int s = 0; s < 2; ++s) {
    f16x8 a0 = *(const f16x8*)(Abase + s * 32);
    f16x8 a1 = *(const f16x8*)(Abase + (size_t)16 * DD + s * 32);
#pragma unroll
    for (int c = 0; c < 8; ++c) {
      f16x8 bf = *(const f16x8*)(Bbase + (size_t)(16 * c) * DD + s * 32);
      acc[0][c] = __builtin_amdgcn_mfma_f32_16x16x32_f16(a0, bf, acc[0][c], 0, 0, 0);
      acc[1][c] = __builtin_amdgcn_mfma_f32_16x16x32_f16(a1, bf, acc[1][c], 0, 0, 0);
    }
  }

  __shared__ unsigned short tile[TS * TS];   // 32 KB
  float4 xr[2];
#pragma unroll
  for (int g = 0; g < 2; ++g)
    xr[g] = *(const float4*)(na + b * NN + i0 + 32 * w + 16 * g + 4 * quad);
#pragma unroll
  for (int c = 0; c < 8; ++c) {
    float yv = nbp[b * MM + j0 + 16 * c + m];
#pragma unroll
    for (int g = 0; g < 2; ++g) {
      float xg[4] = {xr[g].x, xr[g].y, xr[g].z, xr[g].w};
#pragma unroll
      for (int r = 0; r < 4; ++r) {
        float cv = fmaxf(xg[r] + yv - acc[g][c][r], 0.f);
        unsigned int u = __float2uint_rn(fminf(cv * CSCALE, 65535.f));
        tile[(32 * w + 16 * g + 4 * quad + r) * TS + 16 * c + m] = (unsigned short)u;
      }
    }
  }
  __syncthreads();

  const uint4* tl = (const uint4*)tile;   // 2048 uint4 in the tile
#pragma unroll
  for (int p = 0; p < 8; ++p) {
    int u = p * 256 + t;
    int row = u >> 4, c8 = (u & 15) * 8;
    *(uint4*)(Cout + (size_t)(i0 + row) * MM + j0 + c8) = tl[u];
  }
}

// ---------------------------------------------------------------------------
// h-vector prep — used ONCE for the init step (gs = 0); subsequent h's are
// written by merge4.
// ---------------------------------------------------------------------------
__global__ __launch_bounds__(256) void hprep_kernel(
    const float* __restrict__ fab_in, const float* __restrict__ gba_in,
    const float* __restrict__ faa_in, const float* __restrict__ gbb_in,
    float gs)
{
  int i = blockIdx.x * 256 + threadIdx.x;   // grid 64 -> 16384
  g_h0[i] = fmaf(gs, gba_in[i], g_blog[i]);
  g_h1[i] = fmaf(gs, fab_in[i], g_alog[i]);
  g_h2[i] = fmaf(gs, faa_in[i], g_alog[i]);
  g_h3[i] = fmaf(gs, gbb_in[i], g_blog[i]);
}

// ---------------------------------------------------------------------------
// Unified tile-partial softmin pass (verified rounds 8/9, UNCHANGED).
// ---------------------------------------------------------------------------
struct TileArgs {
  const unsigned short* C;
  const float* hrow;
  const float* hcol;
  float2* prow;   // [b][chunk][row]
  float2* pcol;
  int sym;        // 1 => triangular tile enumeration (136 tiles)
};

__global__ __launch_bounds__(256) void tile_pass(
    TileArgs T0, TileArgs T1, TileArgs T2, float inv_eps)
{
  TileArgs A = (blockIdx.z == 0) ? T0 : (blockIdx.z == 1) ? T1 : T2;
  int I, J;
  if (A.sym) {
    if (blockIdx.x >= 136) return;
    int rem = blockIdx.x, ii = 0;
    while (rem >= NCHK - ii) { rem -= NCHK - ii; ++ii; }   // uniform, <=16 iters
    I = ii; J = ii + rem;                                  // I <= J
  } else {
    I = blockIdx.x >> 4;
    J = blockIdx.x & 15;
  }
  const int b = blockIdx.y;
  const int t = threadIdx.x;
  const int ctr = t & 15;   // col-group: tile cols ctr*8 .. +7
  const int rtr = t >> 4;   // row-group: tile rows rtr*8 .. +7
  const float csneg = -inv_eps * CDEC;

  const unsigned short* Cb = A.C + (size_t)b * NMAT
                           + (size_t)(I * TS) * MM + J * TS;

  float hr[8], hc[8];
  {
    const float* hrp = A.hrow + (size_t)b * MM + J * TS + ctr * 8;
    const float* hcp = A.hcol + (size_t)b * MM + I * TS + rtr * 8;
#pragma unroll
    for (int k = 0; k < 8; ++k) { hr[k] = hrp[k]; hc[k] = hcp[k]; }
  }

  // tile chunk -> registers (single global read)
  uint4 cu[8];
#pragma unroll
  for (int r8 = 0; r8 < 8; ++r8)
    cu[r8] = *(const uint4*)(Cb + (size_t)(rtr * 8 + r8) * MM + ctr * 8);

  __shared__ float redR[TS][17], redC[TS][17];   // +1 pad vs bank conflicts
  __shared__ float rowM[TS], colM[TS];

  // ---- phase A: maxes (unpack from registers) ----
  float rm[8], cm[8];
#pragma unroll
  for (int k = 0; k < 8; ++k) { rm[k] = -3.0e38f; cm[k] = -3.0e38f; }
#pragma unroll
  for (int r8 = 0; r8 < 8; ++r8) {
    float base[8];
    base[0] = (float)(cu[r8].x & 0xffff) * csneg;
    base[1] = (float)(cu[r8].x >> 16)    * csneg;
    base[2] = (float)(cu[r8].y & 0xffff) * csneg;
    base[3] = (float)(cu[r8].y >> 16)    * csneg;
    base[4] = (float)(cu[r8].z & 0xffff) * csneg;
    base[5] = (float)(cu[r8].z >> 16)    * csneg;
    base[6] = (float)(cu[r8].w & 0xffff) * csneg;
    base[7] = (float)(cu[r8].w >> 16)    * csneg;
#pragma unroll
    for (int c8 = 0; c8 < 8; ++c8) {
      rm[r8] = fmaxf(rm[r8], hr[c8] + base[c8]);
      cm[c8] = fmaxf(cm[c8], hc[r8] + base[c8]);
    }
  }
#pragma unroll
  for (int r8 = 0; r8 < 8; ++r8) redR[rtr * 8 + r8][ctr] = rm[r8];
#pragma unroll
  for (int c8 = 0; c8 < 8; ++c8) redC[ctr * 8 + c8][rtr] = cm[c8];
  __syncthreads();
  if (t < TS) {
    float m = redR[t][0];
#pragma unroll
    for (int k = 1; k < 16; ++k) m = fmaxf(m, redR[t][k]);
    rowM[t] = m;
  } else {
    int tt = t - TS;
    float m = redC[tt][0];
#pragma unroll
    for (int k = 1; k < 16; ++k) m = fmaxf(m, redC[tt][k]);
    colM[tt] = m;
  }
  __syncthreads();

  float rmv[8], cmv[8];
#pragma unroll
  for (int k = 0; k < 8; ++k) {
    rmv[k] = rowM[rtr * 8 + k];
    cmv[k] = colM[ctr * 8 + k];
  }

  // ---- phase B: sums (unpack same registers again — no global re-read) ----
  float rs[8], cs[8];
#pragma unroll
  for (int k = 0; k < 8; ++k) { rs[k] = 0.f; cs[k] = 0.f; }
#pragma unroll
  for (int r8 = 0; r8 < 8; ++r8) {
    float base[8];
    base[0] = (float)(cu[r8].x & 0xffff) * csneg;
    base[1] = (float)(cu[r8].x >> 16)    * csneg;
    base[2] = (float)(cu[r8].y & 0xffff) * csneg;
    base[3] = (float)(cu[r8].y >> 16)    * csneg;
    base[4] = (float)(cu[r8].z & 0xffff) * csneg;
    base[5] = (float)(cu[r8].z >> 16)    * csneg;
    base[6] = (float)(cu[r8].w & 0xffff) * csneg;
    base[7] = (float)(cu[r8].w >> 16)    * csneg;
#pragma unroll
    for (int c8 = 0; c8 < 8; ++c8) {
      rs[r8] += __expf(hr[c8] + base[c8] - rmv[r8]);
      cs[c8] += __expf(hc[r8] + base[c8] - cmv[c8]);
    }
  }
#pragma unroll
  for (int r8 = 0; r8 < 8; ++r8) redR[rtr * 8 + r8][ctr] = rs[r8];
#pragma unroll
  for (int c8 = 0; c8 < 8; ++c8) redC[ctr * 8 + c8][rtr] = cs[c8];
  __syncthreads();
  if (t < TS) {
    float s = 0.f;
#pragma unroll
    for (int k = 0; k < 16; ++k) s += redR[t][k];
    A.prow[((size_t)b * NCHK + J) * NN + I * TS + t] = make_float2(rowM[t], s);
  } else {
    int tt = t - TS;
    if (!(A.sym && I == J)) {   // diagonal col-dir duplicates row-dir: skip
      float s = 0.f;
#pragma unroll
      for (int k = 0; k < 16; ++k) s += redC[tt][k];
      A.pcol[((size_t)b * NCHK + I) * NN + J * TS + tt] = make_float2(colM[tt], s);
    }
  }
}

// ---------------------------------------------------------------------------
// merge 16 chunk-partials per row -> softmin + Jacobi update + next-h write.
// (verified rounds 8/9, unchanged)
// ---------------------------------------------------------------------------
struct MergeArgs {
  const float2* part;
  const float* fold;
  float* fout;
  const float* hbase;   // alog or blog
  float* hout;          // h vector consumed by the next tile_pass
};

__global__ __launch_bounds__(256) void merge4(
    MergeArgs M0, MergeArgs M1, MergeArgs M2, MergeArgs M3,
    float eps, float alpha, float beta, float nextgs)
{
  MergeArgs A = (blockIdx.z == 0) ? M0 : (blockIdx.z == 1) ? M1
              : (blockIdx.z == 2) ? M2 : M3;
  const int b = blockIdx.y;
  const int i = blockIdx.x * 256 + threadIdx.x;   // grid.x = NN/256
  float2 p[NCHK];
#pragma unroll
  for (int k = 0; k < NCHK; ++k)
    p[k] = A.part[((size_t)b * NCHK + k) * NN + i];
  float M = p[0].x;
#pragma unroll
  for (int k = 1; k < NCHK; ++k) M = fmaxf(M, p[k].x);
  float S = 0.f;
#pragma unroll
  for (int k = 0; k < NCHK; ++k) S += p[k].y * __expf(p[k].x - M);
  float ft = -eps * (M + __logf(S));
  int idx = b * NN + i;
  float fnew = alpha * A.fold[idx] + beta * ft;
  A.fout[idx] = fnew;
  A.hout[idx] = fmaf(nextgs, fnew, A.hbase[idx]);
}

// ---------------------------------------------------------------------------
// loss = mean_b [ sum_i w1*(fabf - faaf) + sum_j w2*(gbaf - gbbf) ]
// ---------------------------------------------------------------------------
__global__ __launch_bounds__(256) void loss_kernel(
    const float* __restrict__ w1, const float* __restrict__ w2,
    float* __restrict__ out)
{
  __shared__ float red[256];
  float acc = 0.f;
  for (int idx = threadIdx.x; idx < NB * NN; idx += 256) {
    acc += w1[idx] * (g_fab[2][idx] - g_faa[2][idx])
         + w2[idx] * (g_gba[2][idx] - g_gbb[2][idx]);
  }
  red[threadIdx.x] = acc;
  __syncthreads();
  for (int s = 128; s > 0; s >>= 1) {
    if (threadIdx.x < s) red[threadIdx.x] += red[threadIdx.x + s];
    __syncthreads();
  }
  if (threadIdx.x == 0) out[0] = red[0] * (1.0f / NB);
}

// ---------------------------------------------------------------------------
extern "C" void kernel_launch(void* const* d_in, const int* in_sizes, int n_in,
                              void* d_out, int out_size, void* d_ws, size_t ws_size,
                              hipStream_t stream)
{
  const float* x = (const float*)d_in[0];
  const float* y = (const float*)d_in[1];
  const float* w1 = (const float*)d_in[2];
  const float* w2 = (const float*)d_in[3];
  float* out = (float*)d_out;

  unsigned short* Cbase;
  hipGetSymbolAddress((void**)&Cbase, HIP_SYMBOL(g_C));
  unsigned short* Cxy = Cbase + 0ull * NB * NMAT;
  unsigned short* Cxx = Cbase + 1ull * NB * NMAT;
  unsigned short* Cyy = Cbase + 2ull * NB * NMAT;
  float *h0, *h1, *h2, *h3, *fabp, *gbap, *faap, *gbbp, *alog, *blog;
  float2 *pfab, *pgba, *pfaa, *pgbb;
  hipGetSymbolAddress((void**)&h0, HIP_SYMBOL(g_h0));
  hipGetSymbolAddress((void**)&h1, HIP_SYMBOL(g_h1));
  hipGetSymbolAddress((void**)&h2, HIP_SYMBOL(g_h2));
  hipGetSymbolAddress((void**)&h3, HIP_SYMBOL(g_h3));
  hipGetSymbolAddress((void**)&fabp, HIP_SYMBOL(g_fab));
  hipGetSymbolAddress((void**)&gbap, HIP_SYMBOL(g_gba));
  hipGetSymbolAddress((void**)&faap, HIP_SYMBOL(g_faa));
  hipGetSymbolAddress((void**)&gbbp, HIP_SYMBOL(g_gbb));
  hipGetSymbolAddress((void**)&alog, HIP_SYMBOL(g_alog));
  hipGetSymbolAddress((void**)&blog, HIP_SYMBOL(g_blog));
  hipGetSymbolAddress((void**)&pfab, HIP_SYMBOL(g_pfab));
  hipGetSymbolAddress((void**)&pgba, HIP_SYMBOL(g_pgba));
  hipGetSymbolAddress((void**)&pfaa, HIP_SYMBOL(g_pfaa));
  hipGetSymbolAddress((void**)&pgbb, HIP_SYMBOL(g_pgbb));

  auto fab = [&](int s) { return fabp + (size_t)s * NB * NN; };
  auto gba = [&](int s) { return gbap + (size_t)s * NB * NN; };
  auto faa = [&](int s) { return faap + (size_t)s * NB * NN; };
  auto gbb = [&](int s) { return gbbp + (size_t)s * NB * NN; };

  // eps schedule (matches the Python double loop, then cast to fp32)
  float eps_list[32];
  int ne = 0;
  {
    double v = 64.0 * 64.0;
    double tgt = 0.05 * 0.05;
    while (v > tgt) { eps_list[ne++] = (float)v; v *= 0.25; }
    eps_list[ne++] = (float)tgt;   // ne == 12
  }

  prep_kernel<<<4096, 256, 0, stream>>>(x, y, w1, w2);

  // all three cost slabs in one dispatch; 128x128 tiles; sym = tri only
  cost_mfma<<<dim3(256, 1, 24), 256, 0, stream>>>();

  dim3 tg(256, NB, 3);          // z: 0=Cxy(256 tiles), 1/2=Cxx/Cyy(tri 136)
  dim3 mg(NN / 256, NB, 4);     // z: potential

  // one iteration: tile_pass (h already in place) + merge4 (writes next h)
  auto launch_iter = [&](float eps, float alpha, float beta, float nextgs,
                         int in, int outsel) {
    float inv = 1.0f / eps;
    TileArgs T0 = {Cxy, h0, h1, pfab, pgba, 0};
    TileArgs T1 = {Cxx, h2, h2, pfaa, pfaa, 1};
    TileArgs T2 = {Cyy, h3, h3, pgbb, pgbb, 1};
    tile_pass<<<tg, 256, 0, stream>>>(T0, T1, T2, inv);
    MergeArgs M0 = {pfab, fab(in), fab(outsel), alog, h1};
    MergeArgs M1 = {pgba, gba(in), gba(outsel), blog, h0};
    MergeArgs M2 = {pfaa, faa(in), faa(outsel), alog, h2};
    MergeArgs M3 = {pgbb, gbb(in), gbb(outsel), blog, h3};
    merge4<<<mg, 256, 0, stream>>>(M0, M1, M2, M3, eps, alpha, beta, nextgs);
  };

  // init at eps0: h = base log-weights (gs=0), alpha=0 -> no carry read;
  // its merge writes h for scan step k=0.
  hprep_kernel<<<64, 256, 0, stream>>>(fab(0), gba(0), faa(0), gbb(0), 0.f);
  launch_iter(eps_list[0], 0.f, 1.f, 1.0f / eps_list[0], 0, 0);

  // scan over the full eps list with 0.5-averaging (Jacobi, banks 0/1);
  // each merge writes h for the NEXT step (k+1, or the final extrapolation).
  int cur = 0;
  for (int k = 0; k < ne; ++k) {
    int nxt = 1 - cur;
    float nextgs = 1.0f / ((k < ne - 1) ? eps_list[k + 1] : eps_list[ne - 1]);
    launch_iter(eps_list[k], 0.5f, 0.5f, nextgs, cur, nxt);
    cur = nxt;
  }

  // final extrapolation at eps = blur^p (no averaging) -> bank 2
  launch_iter(eps_list[ne - 1], 0.f, 1.f, 0.f, cur, 2);

  loss_kernel<<<1, 256, 0, stream>>>(w1, w2, out);
}